// Round 8
// baseline (168.671 us; speedup 1.0000x reference)
//
#include <hip/hip_runtime.h>

#define SEQ  2048
#define HID  128
#define NB   32
#define TILE 58            // owned output rows per block
#define GX   36            // ceil(2048/58)
#define TSTR 132           // tbuf row stride (floats), row-major t[m][n]
#define RSTR 2080          // frag region stride (shorts): 4*512 + 32 pad

typedef float f2     __attribute__((ext_vector_type(2)));
typedef float f32x4  __attribute__((ext_vector_type(4)));
typedef short bf16x8 __attribute__((ext_vector_type(8)));
typedef short s4v    __attribute__((ext_vector_type(4)));

// split v ~= hi + lo; hi RNE, lo truncated (lo error ~2^-18 relative: harmless)
__device__ __forceinline__ void split_bf16(float v, short& h, short& l) {
  unsigned u = __float_as_uint(v);
  unsigned r = (u + 0x7fffu + ((u >> 16) & 1u)) >> 16;
  h = (short)r;
  const float lo = v - __uint_as_float(r << 16);
  l = (short)(__float_as_uint(lo) >> 16);
}

// ---------------------------------------------------------------------------
// prep_kernel (validated R7): B-fragments bf16 hi/lo for W'=enc_w2@gc1_w,
// gc2_w, gc3_w; b' = enc_b2@gc1_w + gc1_b.
//   dest = L*32768 + ((ks*8 + nt)*64 + l)*8 + j  (lo at +16384)
//   src  = W_L[k = ks*32 + (l>>4)*8 + j][n = nt*16 + (l&15)]
// ---------------------------------------------------------------------------
__global__ __launch_bounds__(256) void prep_kernel(
    const float* __restrict__ enc_w2, const float* __restrict__ enc_b2,
    const float* __restrict__ gc1_w, const float* __restrict__ gc1_b,
    const float* __restrict__ gc2_w, const float* __restrict__ gc3_w,
    short* __restrict__ Wf, float* __restrict__ bp)
{
  __shared__ float Wls[32][130];
  __shared__ float ew2s[32][128];
  __shared__ float bsum[2][128];

  const int ks = blockIdx.x;
  const int L  = blockIdx.y;
  const int tid = threadIdx.x;

  if (L == 0) {
    for (int f = tid; f < 32 * 128; f += 256)
      ew2s[f >> 7][f & 127] = enc_w2[(ks * 32 + (f >> 7)) * 128 + (f & 127)];
    __syncthreads();
    {
      const int c = tid & 127, rh = tid >> 7;
      float acc[16];
      #pragma unroll
      for (int i = 0; i < 16; ++i) acc[i] = 0.f;
      #pragma unroll 4
      for (int k = 0; k < 128; ++k) {
        const float g = gc1_w[k * 128 + c];
        #pragma unroll
        for (int i = 0; i < 16; ++i)
          acc[i] = fmaf(ew2s[rh * 16 + i][k], g, acc[i]);
      }
      #pragma unroll
      for (int i = 0; i < 16; ++i) Wls[rh * 16 + i][c] = acc[i];
    }
    if (ks == 0) {
      const int c = tid & 127, kh = tid >> 7;
      float s = 0.f;
      #pragma unroll 4
      for (int k0 = 0; k0 < 64; ++k0) {
        const int k = kh * 64 + k0;
        s = fmaf(enc_b2[k], gc1_w[k * 128 + c], s);
      }
      bsum[kh][c] = s;
    }
    __syncthreads();
    if (ks == 0 && tid < 128) bp[tid] = gc1_b[tid] + bsum[0][tid] + bsum[1][tid];
  } else {
    const float* SW = (L == 1) ? gc2_w : gc3_w;
    for (int f = tid; f < 32 * 128; f += 256)
      Wls[f >> 7][f & 127] = SW[(ks * 32 + (f >> 7)) * 128 + (f & 127)];
    __syncthreads();
  }

  short* hi = Wf + L * 32768 + ks * 4096;
  short* lo = hi + 16384;
  for (int f = tid; f < 4096; f += 256) {
    const int nt = f >> 9, l = (f >> 3) & 63, j = f & 7;
    const int kk = (l >> 4) * 8 + j;
    const int n  = nt * 16 + (l & 15);
    short h, lw;
    split_bf16(Wls[kk][n], h, lw);
    hi[f] = h; lo[f] = lw;
  }
}

// ---------------------------------------------------------------------------
// Fused enc1 -> [enc2*gc1] -> gc2 -> gc3 -> pool, MFMA bf16x3 with
// precomputed A-fragments (frag-linear LDS, coalesced b128 reads).
// Per layer: MFMA (frag reads) | epilogue t -> tbuf[m][n] | agg+split pass
// (float4 reads, b64 frag writes). enc1 writes its frags directly.
// Frag-linear: addr_shorts = (m>>4)*RSTR + ks*512 + ((m&15)|(oct<<4))*8 + j,
// where k = ks*32 + oct*8 + j; reader wave w: region w, b128 at lane*8.
// LDS: tbuf 33792 B + 2 frag bufs 2*16640 B = 67072 B -> 2 blocks/CU.
// ---------------------------------------------------------------------------
__global__ __launch_bounds__(256) void fused_kernel(
    const float* __restrict__ x,
    const float* __restrict__ enc_w1, const float* __restrict__ enc_b1,
    const short* __restrict__ Wf, const float* __restrict__ bp,
    const float* __restrict__ gc2_b, const float* __restrict__ gc3_b,
    float* __restrict__ partial)
{
  __shared__ __align__(16) float smem[8448 + 8320];  // 67072 B
  float* tbuf = smem;                                // [64][TSTR]
  short* fh   = (short*)(smem + 8448);               // frag hi, 4*RSTR shorts
  short* fl   = fh + 4 * RSTR;                       // frag lo
  float* wsmall = smem;                              // enc_w1+b1 (dead before tbuf use)
  float* psum   = smem + 8448;                       // overlays frags (dead at pool)

  const int tid  = threadIdx.x;
  const int lane = tid & 63;
  const int w    = tid >> 6;
  const int gxb  = blockIdx.x, b = blockIdx.y;
  const int s0   = gxb * TILE;
  const float inv2 = 1.0f / (2.0f + 1e-8f), inv3 = 1.0f / (3.0f + 1e-8f);

  // ---------------- enc1: h1 = relu(x@w1+b1) -> A-frags directly ----------
  for (int f = tid; f < 7 * HID; f += 256)
    wsmall[f] = (f < 6 * HID) ? enc_w1[f] : enc_b1[f - 6 * HID];

  const int sm = s0 - 3 + lane;          // lane = staged row m
  float xv[6];
  if (sm >= 0 && sm < SEQ) {
    const f2* xp = (const f2*)(x + ((long long)b * SEQ + sm) * 6);
    const f2 a0 = xp[0], a1 = xp[1], a2 = xp[2];
    xv[0] = a0.x; xv[1] = a0.y; xv[2] = a1.x;
    xv[3] = a1.y; xv[4] = a2.x; xv[5] = a2.y;
  } else {
    #pragma unroll
    for (int k = 0; k < 6; ++k) xv[k] = 0.f;
  }
  __syncthreads();
  {
    const int c0 = w * 32;
    float4 a4[8];
    #pragma unroll
    for (int q = 0; q < 8; ++q) a4[q] = make_float4(0.f, 0.f, 0.f, 0.f);
    #pragma unroll
    for (int k = 0; k < 6; ++k) {
      #pragma unroll
      for (int q = 0; q < 8; ++q) {
        const float4 wv = *(const float4*)&wsmall[k * HID + c0 + q * 4];
        a4[q].x = fmaf(xv[k], wv.x, a4[q].x);
        a4[q].y = fmaf(xv[k], wv.y, a4[q].y);
        a4[q].z = fmaf(xv[k], wv.z, a4[q].z);
        a4[q].w = fmaf(xv[k], wv.w, a4[q].w);
      }
    }
    // bias + relu, split, write frags: region = lane>>4, ks = w
    short* fhW = fh + (lane >> 4) * RSTR + w * 512;
    short* flW = fl + (lane >> 4) * RSTR + w * 512;
    #pragma unroll
    for (int oct = 0; oct < 4; ++oct) {
      float v[8];
      #pragma unroll
      for (int h = 0; h < 2; ++h) {
        const int q = 2 * oct + h;
        const float4 bb = *(const float4*)&wsmall[6 * HID + c0 + q * 4];
        v[4*h+0] = fmaxf(a4[q].x + bb.x, 0.f);
        v[4*h+1] = fmaxf(a4[q].y + bb.y, 0.f);
        v[4*h+2] = fmaxf(a4[q].z + bb.z, 0.f);
        v[4*h+3] = fmaxf(a4[q].w + bb.w, 0.f);
      }
      bf16x8 hs, ls;
      #pragma unroll
      for (int j = 0; j < 8; ++j) { short hh, ll; split_bf16(v[j], hh, ll); hs[j] = hh; ls[j] = ll; }
      const int off = (((lane & 15) | (oct << 4))) * 8;
      *(bf16x8*)(fhW + off) = hs;
      *(bf16x8*)(flW + off) = ls;
    }
  }
  __syncthreads();

  // ---------------- 3 MFMA layers ----------------
  const int n0 = lane & 15;
  const int mrow0 = w * 16 + (lane >> 4) * 4;

  #pragma unroll 1
  for (int L = 0; L < 3; ++L) {
    const short* WfL = Wf + L * 32768;
    const bf16x8* Bhi = (const bf16x8*)WfL;
    const bf16x8* Blo = (const bf16x8*)(WfL + 16384);
    const float* bias = (L == 0) ? bp : (L == 1) ? gc2_b : gc3_b;

    f32x4 acc[8];
    #pragma unroll
    for (int nt = 0; nt < 8; ++nt) acc[nt] = (f32x4){0.f, 0.f, 0.f, 0.f};

    #pragma unroll 1
    for (int ks = 0; ks < 4; ++ks) {
      const int fb = ks * 512 + lane;
      bf16x8 bh[8], bl[8];
      #pragma unroll
      for (int nt = 0; nt < 8; ++nt) {
        bh[nt] = Bhi[fb + nt * 64];
        bl[nt] = Blo[fb + nt * 64];
      }
      const int fa = w * RSTR + ks * 512 + lane * 8;
      const bf16x8 ah = *(const bf16x8*)(fh + fa);
      const bf16x8 al = *(const bf16x8*)(fl + fa);
      #pragma unroll
      for (int nt = 0; nt < 8; ++nt) {
        acc[nt] = __builtin_amdgcn_mfma_f32_16x16x32_bf16(ah, bh[nt], acc[nt], 0, 0, 0);
        acc[nt] = __builtin_amdgcn_mfma_f32_16x16x32_bf16(ah, bl[nt], acc[nt], 0, 0, 0);
        acc[nt] = __builtin_amdgcn_mfma_f32_16x16x32_bf16(al, bh[nt], acc[nt], 0, 0, 0);
      }
    }
    __syncthreads();   // frag reads done (frags may be overwritten by agg)

    // epilogue: t = inseq ? acc + bias : 0 -> tbuf[m][n] (C/D scatter)
    #pragma unroll
    for (int nt = 0; nt < 8; ++nt) {
      const float bn = bias[nt * 16 + n0];
      #pragma unroll
      for (int r = 0; r < 4; ++r) {
        const int m = mrow0 + r;
        const int s = s0 - 3 + m;
        const bool vld = (s >= 0 && s < SEQ);
        tbuf[m * TSTR + nt * 16 + n0] = vld ? (acc[nt][r] + bn) : 0.f;
      }
    }
    __syncthreads();   // publish t

    if (L < 2) {
      // agg + relu + split -> next layer's A-frags (float4 reads, b64 writes)
      #pragma unroll
      for (int i = 0; i < 8; ++i) {
        const int task = i * 256 + tid;
        const int m = task >> 5, kq = task & 31, k0 = kq * 4;
        const int mm = (m == 0) ? 0 : m - 1;
        const int mp = (m == 63) ? 63 : m + 1;
        const float4 A = *(const float4*)&tbuf[mm * TSTR + k0];
        const float4 Bv = *(const float4*)&tbuf[m  * TSTR + k0];
        const float4 Cv = *(const float4*)&tbuf[mp * TSTR + k0];
        const int s = s0 - 3 + m;
        const float invd = (s == 0 || s == SEQ - 1) ? inv2 : inv3;
        float v[4];
        v[0] = fmaxf((A.x + Bv.x + Cv.x) * invd, 0.f);
        v[1] = fmaxf((A.y + Bv.y + Cv.y) * invd, 0.f);
        v[2] = fmaxf((A.z + Bv.z + Cv.z) * invd, 0.f);
        v[3] = fmaxf((A.w + Bv.w + Cv.w) * invd, 0.f);
        s4v hs, ls;
        #pragma unroll
        for (int j = 0; j < 4; ++j) { short hh, ll; split_bf16(v[j], hh, ll); hs[j] = hh; ls[j] = ll; }
        const int base = (m >> 4) * RSTR + (kq >> 3) * 512 +
                         (((m & 15) | (((kq >> 1) & 3) << 4))) * 8 + (kq & 1) * 4;
        *(s4v*)(fh + base) = hs;
        *(s4v*)(fl + base) = ls;
      }
      __syncthreads();  // publish frags for next layer
    }
  }

  // ---------------- pool: h3 = relu(agg(t3)); running window ----------------
  {
    const int c = tid & 127, g2 = tid >> 7;
    const int mstart = 3 + g2 * 29;
    float prev = tbuf[(mstart - 1) * TSTR + c];
    float cur  = tbuf[mstart * TSTR + c];
    float ps = 0.f;
    #pragma unroll 1
    for (int r = 0; r < 29; ++r) {
      const int m = mstart + r;
      const int s = s0 + g2 * 29 + r;
      const float nxt = tbuf[(m + 1) * TSTR + c];
      if (s < SEQ) {
        const float invd = (s == 0 || s == SEQ - 1) ? inv2 : inv3;
        ps += fmaxf((prev + cur + nxt) * invd, 0.f);
      }
      prev = cur; cur = nxt;
    }
    psum[tid] = ps;    // psum overlays frag area (dead after L2 MFMA)
  }
  __syncthreads();
  if (tid < 128)
    partial[((long long)b * GX + gxb) * HID + tid] = psum[tid] + psum[tid + 128];
}

// ---------------------------------------------------------------------------
// Classifier (validated R7): reduce partials -> mean -> MLP head
// ---------------------------------------------------------------------------
__global__ __launch_bounds__(256) void cls_kernel(
    const float* __restrict__ partial,
    const float* __restrict__ w1, const float* __restrict__ b1,
    const float* __restrict__ w2, const float* __restrict__ b2,
    float* __restrict__ out)
{
  __shared__ float red[256];
  __shared__ float ms[128];
  __shared__ float hp[4][64];
  __shared__ float hid[64];
  const int b = blockIdx.x, tid = threadIdx.x;

  {
    const int c = tid & 127, gh = tid >> 7;
    float a = 0.f;
    #pragma unroll 2
    for (int g = gh; g < GX; g += 2)
      a += partial[((long long)b * GX + g) * HID + c];
    red[tid] = a;
  }
  __syncthreads();
  if (tid < 128) ms[tid] = (red[tid] + red[tid + 128]) * (1.0f / 2048.0f);
  __syncthreads();
  {
    const int c = tid & 63, kq = tid >> 6;
    float h = 0.f;
    #pragma unroll 8
    for (int k0 = 0; k0 < 32; ++k0) {
      const int k = kq * 32 + k0;
      h = fmaf(ms[k], w1[k * 64 + c], h);
    }
    hp[kq][c] = h;
  }
  __syncthreads();
  if (tid < 64)
    hid[tid] = fmaxf(hp[0][tid] + hp[1][tid] + hp[2][tid] + hp[3][tid] + b1[tid], 0.f);
  __syncthreads();
  if (tid < 3) {
    float o = b2[tid];
    #pragma unroll 8
    for (int k = 0; k < 64; ++k) o = fmaf(hid[k], w2[k * 3 + tid], o);
    out[b * 3 + tid] = o;
  }
}

extern "C" void kernel_launch(void* const* d_in, const int* in_sizes, int n_in,
                              void* d_out, int out_size, void* d_ws, size_t ws_size,
                              hipStream_t stream) {
  (void)in_sizes; (void)n_in; (void)out_size; (void)ws_size;
  const float* x      = (const float*)d_in[0];
  const float* enc_w1 = (const float*)d_in[1];
  const float* enc_b1 = (const float*)d_in[2];
  const float* enc_w2 = (const float*)d_in[3];
  const float* enc_b2 = (const float*)d_in[4];
  const float* gc1_w  = (const float*)d_in[5];
  const float* gc1_b  = (const float*)d_in[6];
  const float* gc2_w  = (const float*)d_in[7];
  const float* gc2_b  = (const float*)d_in[8];
  const float* gc3_w  = (const float*)d_in[9];
  const float* gc3_b  = (const float*)d_in[10];
  const float* cls_w1 = (const float*)d_in[11];
  const float* cls_b1 = (const float*)d_in[12];
  const float* cls_w2 = (const float*)d_in[13];
  const float* cls_b2 = (const float*)d_in[14];

  short* Wfrag   = (short*)d_ws;                     // 3*2*16384 bf16
  float* bpv     = (float*)(Wfrag + 3 * 2 * 16384);  // 128 f32
  float* partial = bpv + 128;                        // NB*GX*HID f32

  prep_kernel<<<dim3(4, 3), 256, 0, stream>>>(
      enc_w2, enc_b2, gc1_w, gc1_b, gc2_w, gc3_w, Wfrag, bpv);
  fused_kernel<<<dim3(GX, NB), 256, 0, stream>>>(
      x, enc_w1, enc_b1, Wfrag, bpv, gc2_b, gc3_b, partial);
  cls_kernel<<<dim3(NB), 256, 0, stream>>>(partial, cls_w1, cls_b1, cls_w2, cls_b2,
                                           (float*)d_out);
}

// Round 10
// 150.437 us; speedup vs baseline: 1.1212x; 1.1212x over previous
//
#include <hip/hip_runtime.h>

#define SEQ  2048
#define HID  128
#define NB   32
#define TILE 58            // owned output rows per block
#define GX   36            // ceil(2048/58)
#define MSTR 67            // hT row stride: hT[k][m], k=0..127, m=0..63 (+pad)

typedef float f2     __attribute__((ext_vector_type(2)));
typedef float f32x4  __attribute__((ext_vector_type(4)));
typedef short bf16x8 __attribute__((ext_vector_type(8)));

// split v into bf16 hi + bf16 lo (RNE both); v ~= hi + lo to ~16 mantissa bits
__device__ __forceinline__ void split_bf16(float v, short& h, short& l) {
  unsigned u = __float_as_uint(v);
  unsigned r = (u + 0x7fffu + ((u >> 16) & 1u)) >> 16;
  h = (short)r;
  const float hf = __uint_as_float(r << 16);
  const float lo = v - hf;
  unsigned u2 = __float_as_uint(lo);
  unsigned r2 = (u2 + 0x7fffu + ((u2 >> 16) & 1u)) >> 16;
  l = (short)r2;
}

// single RNE bf16 (activation path: a_lo dropped; pooling averages the
// zero-mean rounding error -> est. final absmax <1e-5 vs 1.4e-3 threshold)
__device__ __forceinline__ short cvt_bf16(float v) {
  unsigned u = __float_as_uint(v);
  return (short)((u + 0x7fffu + ((u >> 16) & 1u)) >> 16);
}

// ---------------------------------------------------------------------------
// prep_kernel (validated R7): B-fragments bf16 hi/lo for W'=enc_w2@gc1_w,
// gc2_w, gc3_w; b' = enc_b2@gc1_w + gc1_b.
//   dest = L*32768 + ((ks*8 + nt)*64 + l)*8 + j  (lo at +16384)
//   src  = W_L[k = ks*32 + (l>>4)*8 + j][n = nt*16 + (l&15)]
// ---------------------------------------------------------------------------
__global__ __launch_bounds__(256) void prep_kernel(
    const float* __restrict__ enc_w2, const float* __restrict__ enc_b2,
    const float* __restrict__ gc1_w, const float* __restrict__ gc1_b,
    const float* __restrict__ gc2_w, const float* __restrict__ gc3_w,
    short* __restrict__ Wf, float* __restrict__ bp)
{
  __shared__ float Wls[32][130];
  __shared__ float ew2s[32][128];
  __shared__ float bsum[2][128];

  const int ks = blockIdx.x;
  const int L  = blockIdx.y;
  const int tid = threadIdx.x;

  if (L == 0) {
    for (int f = tid; f < 32 * 128; f += 256)
      ew2s[f >> 7][f & 127] = enc_w2[(ks * 32 + (f >> 7)) * 128 + (f & 127)];
    __syncthreads();
    {
      const int c = tid & 127, rh = tid >> 7;
      float acc[16];
      #pragma unroll
      for (int i = 0; i < 16; ++i) acc[i] = 0.f;
      #pragma unroll 4
      for (int k = 0; k < 128; ++k) {
        const float g = gc1_w[k * 128 + c];
        #pragma unroll
        for (int i = 0; i < 16; ++i)
          acc[i] = fmaf(ew2s[rh * 16 + i][k], g, acc[i]);
      }
      #pragma unroll
      for (int i = 0; i < 16; ++i) Wls[rh * 16 + i][c] = acc[i];
    }
    if (ks == 0) {
      const int c = tid & 127, kh = tid >> 7;
      float s = 0.f;
      #pragma unroll 4
      for (int k0 = 0; k0 < 64; ++k0) {
        const int k = kh * 64 + k0;
        s = fmaf(enc_b2[k], gc1_w[k * 128 + c], s);
      }
      bsum[kh][c] = s;
    }
    __syncthreads();
    if (ks == 0 && tid < 128) bp[tid] = gc1_b[tid] + bsum[0][tid] + bsum[1][tid];
  } else {
    const float* SW = (L == 1) ? gc2_w : gc3_w;
    for (int f = tid; f < 32 * 128; f += 256)
      Wls[f >> 7][f & 127] = SW[(ks * 32 + (f >> 7)) * 128 + (f & 127)];
    __syncthreads();
  }

  short* hi = Wf + L * 32768 + ks * 4096;
  short* lo = hi + 16384;
  for (int f = tid; f < 4096; f += 256) {
    const int nt = f >> 9, l = (f >> 3) & 63, j = f & 7;
    const int kk = (l >> 4) * 8 + j;
    const int n  = nt * 16 + (l & 15);
    short h, lw;
    split_bf16(Wls[kk][n], h, lw);
    hi[f] = h; lo[f] = lw;
  }
}

// ---------------------------------------------------------------------------
// Fused enc1 -> [enc2*gc1 folded] -> gc2 -> gc3 -> pool partials.
// R7-validated structure; MFMA inner product reduced to 2 terms:
// D = a_hi*(W_hi + W_lo)  (a_lo dropped — see error analysis).
// ---------------------------------------------------------------------------
__global__ __launch_bounds__(256) void fused_kernel(
    const float* __restrict__ x,
    const float* __restrict__ enc_w1, const float* __restrict__ enc_b1,
    const short* __restrict__ Wf, const float* __restrict__ bp,
    const float* __restrict__ gc2_b, const float* __restrict__ gc3_b,
    float* __restrict__ partial)
{
  __shared__ float hT[HID * MSTR];      // 34304 B, [k][m]
  __shared__ float wsmall[7 * HID];     // enc_w1 (6x128) + enc_b1
  __shared__ float psum[256];

  const int tid  = threadIdx.x;
  const int lane = tid & 63;
  const int w    = tid >> 6;            // wave id 0..3
  const int gxb  = blockIdx.x, b = blockIdx.y;
  const int s0   = gxb * TILE;

  // ---------------- enc1 (fp32 VALU): lane = row m, wave = 32-col group ----
  for (int f = tid; f < 7 * HID; f += 256)
    wsmall[f] = (f < 6 * HID) ? enc_w1[f] : enc_b1[f - 6 * HID];

  const int sm = s0 - 3 + lane;
  float xv[6];
  if (sm >= 0 && sm < SEQ) {
    const f2* xp = (const f2*)(x + ((long long)b * SEQ + sm) * 6);
    const f2 a0 = xp[0], a1 = xp[1], a2 = xp[2];
    xv[0] = a0.x; xv[1] = a0.y; xv[2] = a1.x;
    xv[3] = a1.y; xv[4] = a2.x; xv[5] = a2.y;
  } else {
    #pragma unroll
    for (int k = 0; k < 6; ++k) xv[k] = 0.f;
  }
  __syncthreads();
  {
    const int c0 = w * 32;
    float4 a4[8];
    #pragma unroll
    for (int q = 0; q < 8; ++q) a4[q] = make_float4(0.f, 0.f, 0.f, 0.f);
    #pragma unroll
    for (int k = 0; k < 6; ++k) {
      #pragma unroll
      for (int q = 0; q < 8; ++q) {
        const float4 wv = *(const float4*)&wsmall[k * HID + c0 + q * 4];
        a4[q].x = fmaf(xv[k], wv.x, a4[q].x);
        a4[q].y = fmaf(xv[k], wv.y, a4[q].y);
        a4[q].z = fmaf(xv[k], wv.z, a4[q].z);
        a4[q].w = fmaf(xv[k], wv.w, a4[q].w);
      }
    }
    #pragma unroll
    for (int q = 0; q < 8; ++q) {
      const float4 bb = *(const float4*)&wsmall[6 * HID + c0 + q * 4];
      const int c = c0 + q * 4;
      hT[(c + 0) * MSTR + lane] = fmaxf(a4[q].x + bb.x, 0.f);
      hT[(c + 1) * MSTR + lane] = fmaxf(a4[q].y + bb.y, 0.f);
      hT[(c + 2) * MSTR + lane] = fmaxf(a4[q].z + bb.z, 0.f);
      hT[(c + 3) * MSTR + lane] = fmaxf(a4[q].w + bb.w, 0.f);
    }
  }
  __syncthreads();

  // ---------------- 3 MFMA layers ----------------
  const int mt   = w * 16 + (lane & 15);       // A-frag target row
  const int koct = (lane >> 4) * 8;            // A-frag k-octet base
  const int stt  = s0 - 3 + mt;
  const float invdA = (stt == 0 || stt == SEQ - 1) ? (1.0f / (2.0f + 1e-8f))
                                                   : (1.0f / (3.0f + 1e-8f));
  const int mm = (mt == 0) ? 0 : mt - 1;
  const int mp = (mt == 63) ? 63 : mt + 1;

  #pragma unroll 1
  for (int L = 0; L < 3; ++L) {
    const short* WfL = Wf + L * 32768;
    const bf16x8* Bhi = (const bf16x8*)WfL;
    const bf16x8* Blo = (const bf16x8*)(WfL + 16384);
    const float* bias = (L == 0) ? bp : (L == 1) ? gc2_b : gc3_b;

    f32x4 acc[8];
    #pragma unroll
    for (int nt = 0; nt < 8; ++nt) acc[nt] = (f32x4){0.f, 0.f, 0.f, 0.f};

    #pragma unroll 1
    for (int ks = 0; ks < 4; ++ks) {
      const int fb = ks * 512 + lane;
      bf16x8 bh[8], bl[8];
      #pragma unroll
      for (int nt = 0; nt < 8; ++nt) {
        bh[nt] = Bhi[fb + nt * 64];
        bl[nt] = Blo[fb + nt * 64];
      }
      // A-frag: read hT (agg+relu for L>0), single RNE bf16 (no lo term)
      bf16x8 ah;
      const float* pa = &hT[(ks * 32 + koct) * MSTR];
      #pragma unroll
      for (int j = 0; j < 8; ++j) {
        float v;
        if (L == 0) {
          v = pa[j * MSTR + mt];
        } else {
          v = (pa[j * MSTR + mm] + pa[j * MSTR + mt] + pa[j * MSTR + mp]) * invdA;
          v = fmaxf(v, 0.f);
        }
        ah[j] = cvt_bf16(v);
      }
      #pragma unroll
      for (int nt = 0; nt < 8; ++nt) {
        acc[nt] = __builtin_amdgcn_mfma_f32_16x16x32_bf16(ah, bh[nt], acc[nt], 0, 0, 0);
        acc[nt] = __builtin_amdgcn_mfma_f32_16x16x32_bf16(ah, bl[nt], acc[nt], 0, 0, 0);
      }
    }
    __syncthreads();   // all hT reads of this layer done

    // epilogue: t = inseq ? acc + bias : 0 -> hT[n][m]  (C/D layout scatter)
    {
      const int n0 = lane & 15;
      const int mrow0 = w * 16 + (lane >> 4) * 4;
      #pragma unroll
      for (int nt = 0; nt < 8; ++nt) {
        const float bn = bias[nt * 16 + n0];
        float* pw = &hT[(nt * 16 + n0) * MSTR];
        #pragma unroll
        for (int r = 0; r < 4; ++r) {
          const int m = mrow0 + r;
          const int s = s0 - 3 + m;
          const bool vld = (s >= 0 && s < SEQ);
          pw[m] = vld ? (acc[nt][r] + bn) : 0.f;
        }
      }
    }
    __syncthreads();   // publish t for next layer / pool
  }

  // ---------------- pool: h3 = relu(agg(t3)); sum owned rows ----------------
  {
    const int c = tid & 127, half = tid >> 7;
    float ps = 0.f;
    const float* pc = &hT[c * MSTR];
    #pragma unroll 1
    for (int r = 0; r < 29; ++r) {
      const int m = 3 + half * 29 + r;
      const int s = s0 + half * 29 + r;
      if (s < SEQ) {
        const float invd = (s == 0 || s == SEQ - 1) ? (1.0f / (2.0f + 1e-8f))
                                                    : (1.0f / (3.0f + 1e-8f));
        ps += fmaxf((pc[m - 1] + pc[m] + pc[m + 1]) * invd, 0.f);
      }
    }
    psum[tid] = ps;
  }
  __syncthreads();
  if (tid < 128)
    partial[((long long)b * GX + gxb) * HID + tid] = psum[tid] + psum[tid + 128];
}

// ---------------------------------------------------------------------------
// Classifier (validated R7): reduce partials -> mean -> MLP head
// ---------------------------------------------------------------------------
__global__ __launch_bounds__(256) void cls_kernel(
    const float* __restrict__ partial,
    const float* __restrict__ w1, const float* __restrict__ b1,
    const float* __restrict__ w2, const float* __restrict__ b2,
    float* __restrict__ out)
{
  __shared__ float red[256];
  __shared__ float ms[128];
  __shared__ float hp[4][64];
  __shared__ float hid[64];
  const int b = blockIdx.x, tid = threadIdx.x;

  {
    const int c = tid & 127, gh = tid >> 7;
    float a = 0.f;
    #pragma unroll 2
    for (int g = gh; g < GX; g += 2)
      a += partial[((long long)b * GX + g) * HID + c];
    red[tid] = a;
  }
  __syncthreads();
  if (tid < 128) ms[tid] = (red[tid] + red[tid + 128]) * (1.0f / 2048.0f);
  __syncthreads();
  {
    const int c = tid & 63, kq = tid >> 6;
    float h = 0.f;
    #pragma unroll 8
    for (int k0 = 0; k0 < 32; ++k0) {
      const int k = kq * 32 + k0;
      h = fmaf(ms[k], w1[k * 64 + c], h);
    }
    hp[kq][c] = h;
  }
  __syncthreads();
  if (tid < 64)
    hid[tid] = fmaxf(hp[0][tid] + hp[1][tid] + hp[2][tid] + hp[3][tid] + b1[tid], 0.f);
  __syncthreads();
  if (tid < 3) {
    float o = b2[tid];
    #pragma unroll 8
    for (int k = 0; k < 64; ++k) o = fmaf(hid[k], w2[k * 3 + tid], o);
    out[b * 3 + tid] = o;
  }
}

extern "C" void kernel_launch(void* const* d_in, const int* in_sizes, int n_in,
                              void* d_out, int out_size, void* d_ws, size_t ws_size,
                              hipStream_t stream) {
  (void)in_sizes; (void)n_in; (void)out_size; (void)ws_size;
  const float* x      = (const float*)d_in[0];
  const float* enc_w1 = (const float*)d_in[1];
  const float* enc_b1 = (const float*)d_in[2];
  const float* enc_w2 = (const float*)d_in[3];
  const float* enc_b2 = (const float*)d_in[4];
  const float* gc1_w  = (const float*)d_in[5];
  const float* gc1_b  = (const float*)d_in[6];
  const float* gc2_w  = (const float*)d_in[7];
  const float* gc2_b  = (const float*)d_in[8];
  const float* gc3_w  = (const float*)d_in[9];
  const float* gc3_b  = (const float*)d_in[10];
  const float* cls_w1 = (const float*)d_in[11];
  const float* cls_b1 = (const float*)d_in[12];
  const float* cls_w2 = (const float*)d_in[13];
  const float* cls_b2 = (const float*)d_in[14];

  short* Wfrag   = (short*)d_ws;                     // 3*2*16384 bf16
  float* bpv     = (float*)(Wfrag + 3 * 2 * 16384);  // 128 f32
  float* partial = bpv + 128;                        // NB*GX*HID f32

  prep_kernel<<<dim3(4, 3), 256, 0, stream>>>(
      enc_w2, enc_b2, gc1_w, gc1_b, gc2_w, gc3_w, Wfrag, bpv);
  fused_kernel<<<dim3(GX, NB), 256, 0, stream>>>(
      x, enc_w1, enc_b1, Wfrag, bpv, gc2_b, gc3_b, partial);
  cls_kernel<<<dim3(NB), 256, 0, stream>>>(partial, cls_w1, cls_b1, cls_w2, cls_b2,
                                           (float*)d_out);
}